// Round 9
// baseline (239.004 us; speedup 1.0000x reference)
//
#include <hip/hip_runtime.h>
#include <hip/hip_bf16.h>
#include <cstdint>

#define KDIM 512
#define BM 64       // rows per block
#define BN 512      // full N per block
#define BK 32
#define M_MAIN 100352   // 512*196
#define NPIX 196
#define BATCH 512

typedef float f32x4 __attribute__((ext_vector_type(4)));
typedef short s16x8 __attribute__((ext_vector_type(8)));

#define SCHED0 __builtin_amdgcn_sched_barrier(0)

__device__ __forceinline__ short f2bf(float f) {
    uint32_t u = __float_as_uint(f);
    uint32_t r = u + 0x7FFFu + ((u >> 16) & 1u);   // round-to-nearest-even
    return (short)(r >> 16);
}

__device__ __forceinline__ void gload_lds16(const void* g, void* l) {
    __builtin_amdgcn_global_load_lds(
        (const __attribute__((address_space(1))) void*)g,
        (__attribute__((address_space(3))) void*)l, 16, 0, 0);
}

__device__ __forceinline__ uint32_t pkbf(float lo, float hi) {
    __hip_bfloat162 p = __float22bfloat162_rn(float2{lo, hi});
    return *reinterpret_cast<uint32_t*>(&p);
}

// Transpose + convert W [K][A] fp32 -> Wt [A][K] bf16 for both weight matrices.
__global__ void prep_w(const float* __restrict__ W_enc, const float* __restrict__ W_dec,
                       short* __restrict__ Wt_enc, short* __restrict__ Wt_dec) {
    int a = blockIdx.x;
    int k = threadIdx.x;
    const float* W = blockIdx.y ? W_dec : W_enc;
    short* Wt = blockIdx.y ? Wt_dec : Wt_enc;
    Wt[a * KDIM + k] = f2bf(W[(size_t)k * KDIM + a]);
}

// A-direct GEMM: A fragments are loaded global->reg in MFMA layout (lane l:
// row l&15, k (l>>4)*8..+7 = one contiguous 32B read) and converted with
// cvt_pk -- A never touches LDS, so barriers/LDS serve only B.
// 64x512 tile, BK=32, 256 thr = 4 waves (1M x 4N), wave-tile 64x128
// (acc[4][8]).  B (Wt, L2-hot) double-buffered via global_load_lds with R8's
// measured-conflict-free BK=32 swizzle (source pre-swizzled, rule #21).
// Pipeline: per tile issue A(t+2) regs + B(t+1) gload; ONE raw s_barrier per
// tile preceded by counted vmcnt(8) -- issue order (A first, B second) makes
// the drain retire exactly B(t+1), leaving A(t+2)'s 8 loads in flight.
// EPI==0: out[row][col] = acc + b1[col] + b2[col]   (att_dec' precompute)
// EPI==1: out[row] = full energy = sum_cols relu(acc + attdec[row/196][col]) * wfull[col]
template <int EPI>
__launch_bounds__(256, 2)
__global__ void gemm_fused(const float* __restrict__ A, int M,
                           const short* __restrict__ Bt,
                           const float* __restrict__ b1, const float* __restrict__ b2,
                           const float* __restrict__ attdec, const float* __restrict__ wfull,
                           float* __restrict__ outp) {
    __shared__ short lds_b[2][BN][BK];   // 64 KB (B only)

    const int tid = threadIdx.x;
    const int wave = tid >> 6;      // = wn (0..3), 128 cols each
    const int lane = tid & 63;
    const int lcol = lane & 15;
    const int lk8 = (lane >> 4) * 8;        // k-offset within BK=32
    const int lrg = (lane >> 4) * 4;        // C-row group
    const int r0 = blockIdx.x * BM;

    f32x4 rawA[4][2];
    auto loadAraw = [&](int kt) {
#pragma unroll
        for (int fm = 0; fm < 4; ++fm) {
            const float* p = A + (size_t)(r0 + fm * 16 + lcol) * KDIM + kt * BK + lk8;
            rawA[fm][0] = *(const f32x4*)p;
            rawA[fm][1] = *(const f32x4*)(p + 4);
        }
    };
    auto convA = [&](s16x8 (&af)[4]) {
#pragma unroll
        for (int fm = 0; fm < 4; ++fm) {
            union { s16x8 s; uint32_t u[4]; } r;
            r.u[0] = pkbf(rawA[fm][0][0], rawA[fm][0][1]);
            r.u[1] = pkbf(rawA[fm][0][2], rawA[fm][0][3]);
            r.u[2] = pkbf(rawA[fm][1][0], rawA[fm][1][1]);
            r.u[3] = pkbf(rawA[fm][1][2], rawA[fm][1][3]);
            af[fm] = r.s;
        }
    };
    auto stageB = [&](int buf, int kt) {
#pragma unroll
        for (int i = 0; i < 8; ++i) {
            int rb = wave * 128 + i * 16;   // 16 rows per issue (64B rows)
            int srcsl = (lane & 3) ^ ((lane >> 3) & 3);   // pre-swizzled source slot
            const short* g = Bt + (size_t)(rb + (lane >> 2)) * KDIM + kt * BK + srcsl * 8;
            gload_lds16(g, &lds_b[buf][rb][0]);
        }
    };
    s16x8 bf[8];
    auto dsReadB = [&](int buf) {
#pragma unroll
        for (int fn = 0; fn < 8; ++fn) {
            int rb = wave * 128 + fn * 16 + lcol;
            int sl = (lane >> 4) ^ ((lcol >> 1) & 3);
            bf[fn] = *(const s16x8*)&lds_b[buf][rb][sl * 8];
        }
    };

    f32x4 acc[4][8];
#pragma unroll
    for (int i = 0; i < 4; ++i)
#pragma unroll
        for (int j = 0; j < 8; ++j)
            acc[i][j] = (f32x4){0.f, 0.f, 0.f, 0.f};

    auto mfma32 = [&](s16x8 (&af)[4]) {
        __builtin_amdgcn_s_setprio(1);
#pragma unroll
        for (int fm = 0; fm < 4; ++fm)
#pragma unroll
            for (int fn = 0; fn < 8; ++fn)
                acc[fm][fn] = __builtin_amdgcn_mfma_f32_16x16x32_bf16(af[fm], bf[fn], acc[fm][fn], 0, 0, 0);
        __builtin_amdgcn_s_setprio(0);
    };

    s16x8 af0[4], af1[4];

    // ---- prologue ----
    loadAraw(0);                 // A(0) x8
    stageB(0, 0);                // B(0) x4-ish issues after A in queue
    convA(af0);                  // compiler auto-waits A(0)
    loadAraw(1);                 // A(1) x8 in flight
    SCHED0;
    asm volatile("s_waitcnt vmcnt(8)" ::: "memory");   // B(0) drained
    __builtin_amdgcn_s_barrier();

    const int nk = KDIM / BK;    // 16
    auto body = [&](int t, s16x8 (&afC)[4], s16x8 (&afN)[4]) {
        const int cur = t & 1;
        stageB(cur ^ 1, t + 1);  // B(t+1) (behind A(t+1) in queue)
        dsReadB(cur);
        mfma32(afC);
        convA(afN);              // auto-wait A(t+1) (vmcnt leaves B in flight)
        loadAraw(t + 2);         // A(t+2) x8
        SCHED0;
        asm volatile("s_waitcnt vmcnt(8)" ::: "memory");   // retire B(t+1); A(t+2) stays
        __builtin_amdgcn_s_barrier();
    };
#pragma unroll 1
    for (int k = 0; k < 7; ++k) {   // tiles 0..13
        body(2 * k, af0, af1);
        body(2 * k + 1, af1, af0);
    }
    // tile 14: stage last B, no more A loads; full drain
    {
        stageB(1, 15);
        dsReadB(0);
        mfma32(af0);
        convA(af1);              // A(15)
        SCHED0;
        asm volatile("s_waitcnt vmcnt(0)" ::: "memory");
        __builtin_amdgcn_s_barrier();
    }
    // tile 15 (no staging)
    dsReadB(1);
    mfma32(af1);

    if constexpr (EPI == 0) {
#pragma unroll
        for (int fm = 0; fm < 4; ++fm)
#pragma unroll
            for (int fn = 0; fn < 8; ++fn) {
                int col = wave * 128 + fn * 16 + lcol;
                float bias = b1[col] + b2[col];
#pragma unroll
                for (int reg = 0; reg < 4; ++reg) {
                    int row = r0 + fm * 16 + lrg + reg;
                    outp[(size_t)row * KDIM + col] = acc[fm][fn][reg] + bias;
                }
            }
    } else {
        // block spans <=2 batch rows (64 < 196): preload both attdec rows
        const int b0 = r0 / NPIX;
        const int b1i = min(b0 + 1, BATCH - 1);
        float wfv[8], ad0[8], ad1[8];
#pragma unroll
        for (int fn = 0; fn < 8; ++fn) {
            int col = wave * 128 + fn * 16 + lcol;
            wfv[fn] = wfull[col];
            ad0[fn] = attdec[(size_t)b0 * KDIM + col];
            ad1[fn] = attdec[(size_t)b1i * KDIM + col];
        }
        // partial energies per wave -> lds_b[0] region (all waves passed tile-14 barrier)
        float* ebuf = reinterpret_cast<float*>(&lds_b[0][0][0]);   // [4][64]
#pragma unroll
        for (int fm = 0; fm < 4; ++fm) {
#pragma unroll
            for (int reg = 0; reg < 4; ++reg) {
                int rl = fm * 16 + lrg + reg;
                bool hi = ((r0 + rl) / NPIX) != b0;
                float es = 0.f;
#pragma unroll
                for (int fn = 0; fn < 8; ++fn) {
                    float ad = hi ? ad1[fn] : ad0[fn];
                    float v = acc[fm][fn][reg] + ad;
                    v = fmaxf(v, 0.f);
                    es = fmaf(v, wfv[fn], es);
                }
#pragma unroll
                for (int m = 1; m < 16; m <<= 1) es += __shfl_xor(es, m);
                if (lcol == 0) ebuf[wave * BM + rl] = es;
            }
        }
        __syncthreads();
        if (tid < BM) {
            float s = (ebuf[tid] + ebuf[BM + tid]) + (ebuf[2 * BM + tid] + ebuf[3 * BM + tid]);
            outp[r0 + tid] = s;
        }
    }
}

// One block per batch element: softmax over 196 energies, write alpha,
// then context[b][e] = sum_p enc[b][p][e] * alpha[p].
__global__ void softmax_ctx(const float* __restrict__ enc, const float* __restrict__ energy,
                            float* __restrict__ out) {
    const int b = blockIdx.x;
    const int t = threadIdx.x;  // 256
    __shared__ float sal[NPIX];
    __shared__ float wred[4];

    float e = (t < NPIX) ? energy[b * NPIX + t] : -1e30f;
    float m = e;
#pragma unroll
    for (int d = 1; d < 64; d <<= 1) m = fmaxf(m, __shfl_xor(m, d));
    if ((t & 63) == 0) wred[t >> 6] = m;
    __syncthreads();
    m = fmaxf(fmaxf(wred[0], wred[1]), fmaxf(wred[2], wred[3]));

    float ex = (t < NPIX) ? __expf(e - m) : 0.f;
    float sm = ex;
#pragma unroll
    for (int d = 1; d < 64; d <<= 1) sm += __shfl_xor(sm, d);
    __syncthreads();
    if ((t & 63) == 0) wred[t >> 6] = sm;
    __syncthreads();
    sm = wred[0] + wred[1] + wred[2] + wred[3];

    float al = ex / sm;
    if (t < NPIX) {
        sal[t] = al;
        out[BATCH * KDIM + b * NPIX + t] = al;
    }
    __syncthreads();

    // context: each thread owns cols 2t, 2t+1
    float c0 = 0.f, c1 = 0.f;
    const float* eb = enc + (size_t)b * NPIX * KDIM;
    const int col = 2 * t;
#pragma unroll 4
    for (int p = 0; p < NPIX; ++p) {
        float a = sal[p];
        float2 v = *(const float2*)(eb + (size_t)p * KDIM + col);
        c0 = fmaf(v.x, a, c0);
        c1 = fmaf(v.y, a, c1);
    }
    out[b * KDIM + col] = c0;
    out[b * KDIM + col + 1] = c1;
}

extern "C" void kernel_launch(void* const* d_in, const int* in_sizes, int n_in,
                              void* d_out, int out_size, void* d_ws, size_t ws_size,
                              hipStream_t stream) {
    const float* encoder = (const float*)d_in[0];   // [512,196,512]
    const float* dec_h   = (const float*)d_in[1];   // [512,512]
    const float* W_enc   = (const float*)d_in[2];   // [512,512]
    const float* b_enc   = (const float*)d_in[3];   // [512]
    const float* W_dec   = (const float*)d_in[4];   // [512,512]
    const float* b_decv  = (const float*)d_in[5];   // [512]
    const float* w_full  = (const float*)d_in[6];   // [512]
    float* out = (float*)d_out;                     // context [512,512] ++ alpha [512,196]

    short* wt_enc = (short*)d_ws;                   // 512*512 bf16
    short* wt_dec = wt_enc + 512 * 512;             // 512*512 bf16
    float* attdec = (float*)(wt_dec + 512 * 512);   // [512][512] fp32 (incl. both biases)
    float* energy = attdec + 512 * 512;             // [100352] fp32 (complete rows)

    // 1) weight transpose + bf16 convert
    prep_w<<<dim3(512, 2), 512, 0, stream>>>(W_enc, W_dec, wt_enc, wt_dec);

    // 2) att_dec' = dec_h @ W_dec + b_dec + b_enc   (store fp32 [512][512])
    gemm_fused<0><<<dim3(512 / BM), 256, 0, stream>>>(dec_h, 512, wt_dec,
                                                      b_enc, b_decv, nullptr, nullptr, attdec);

    // 3) main fused GEMM -> full energies (1568 blocks of 64 rows)
    gemm_fused<1><<<dim3(M_MAIN / BM), 256, 0, stream>>>(encoder, M_MAIN, wt_enc,
                                                         nullptr, nullptr, attdec, w_full, energy);

    // 4) softmax + context
    softmax_ctx<<<dim3(BATCH), 256, 0, stream>>>(encoder, energy, out);
}

// Round 10
// 229.226 us; speedup vs baseline: 1.0427x; 1.0427x over previous
//
#include <hip/hip_runtime.h>
#include <hip/hip_bf16.h>
#include <cstdint>

#define KDIM 512
#define SCOLS 128      // B-slice width per block (persistent in LDS, 128 KB)
#define CHUNK 512      // rows per chunk = 8 waves x 64 rows
#define M_MAIN 100352  // 512*196
#define NPIX 196
#define BATCH 512

typedef float f32x4 __attribute__((ext_vector_type(4)));
typedef short s16x8 __attribute__((ext_vector_type(8)));

__device__ __forceinline__ short f2bf(float f) {
    uint32_t u = __float_as_uint(f);
    uint32_t r = u + 0x7FFFu + ((u >> 16) & 1u);   // round-to-nearest-even
    return (short)(r >> 16);
}

__device__ __forceinline__ void gload_lds16(const void* g, void* l) {
    __builtin_amdgcn_global_load_lds(
        (const __attribute__((address_space(1))) void*)g,
        (__attribute__((address_space(3))) void*)l, 16, 0, 0);
}

__device__ __forceinline__ uint32_t pkbf(float lo, float hi) {
    __hip_bfloat162 p = __float22bfloat162_rn(float2{lo, hi});
    return *reinterpret_cast<uint32_t*>(&p);
}

// Transpose + convert W [K][A] fp32 -> Wt [A][K] bf16 for both weight matrices.
__global__ void prep_w(const float* __restrict__ W_enc, const float* __restrict__ W_dec,
                       short* __restrict__ Wt_enc, short* __restrict__ Wt_dec) {
    int a = blockIdx.x;
    int k = threadIdx.x;
    const float* W = blockIdx.y ? W_dec : W_enc;
    short* Wt = blockIdx.y ? Wt_dec : Wt_enc;
    Wt[a * KDIM + k] = f2bf(W[(size_t)k * KDIM + a]);
}

// Persistent-B, barrier-free GEMM.
// Block owns one 128-col slice of B (Wt rows scol0..+127) loaded ONCE into LDS
// (128 KB, XOR-swizzled: phys 16B-slot p of col c holds logical slot p^(c&7)).
// Then it loops over 512-row chunks of A.  The K=512 loop has NO barriers, NO
// LDS writes, NO waitcnt asm: each of 8 waves owns 64 rows x full 128 cols
// (acc[4][8]); A fragments are loaded global->reg in native MFMA layout
// (lane l: row l&15, k (l>>4)*8 -> one 32B contiguous read), converted with
// cvt_pk, and B fragments ds_read from the static slice.  Compiler schedules
// freely (32 MFMA per K-step hides everything).  A lines hit L2: the 4
// slice-sibling blocks are adjacent after the XCD swizzle -> same-XCD L2 reuse.
// Epilogue is also barrier-free: a wave spans the full slice width, so the
// energy row-sum completes with an in-wave 16-lane shfl reduce.
// EPI==0: out[row][col] = acc + b1[col] + b2[col]   (att_dec' precompute)
// EPI==1: out[slice*M + row] = sum_{cols of slice} relu(acc + attdec[row/196][col]) * wfull[col]
template <int EPI>
__launch_bounds__(512, 1)
__global__ void gemm_fused(const float* __restrict__ A, int M,
                           const short* __restrict__ Bt,
                           const float* __restrict__ b1, const float* __restrict__ b2,
                           const float* __restrict__ attdec, const float* __restrict__ wfull,
                           float* __restrict__ outp) {
    __shared__ short lds_b[SCOLS][KDIM];   // 128 KB, persistent

    const int tid = threadIdx.x;
    const int wv = tid >> 6;        // 8 waves = 8 row-groups of 64
    const int lane = tid & 63;
    const int lcol = lane & 15;
    const int lhi = lane >> 4;
    const int lrg = lhi * 4;

    const int nwg = gridDim.x;
    int w = blockIdx.x;
    if ((nwg & 7) == 0) {           // bijective XCD swizzle; slice-siblings stay adjacent
        int q = nwg >> 3;
        w = (blockIdx.x & 7) * q + (blockIdx.x >> 3);
    }
    const int slice = w & 3;
    const int bps = nwg >> 2;       // blocks per slice
    const int scol0 = slice * SCOLS;
    const int nch = M / CHUNK;

    // ---- B slice -> LDS once (source slot pre-swizzled, rule #21) ----
#pragma unroll
    for (int i = 0; i < 16; ++i) {
        int col = i * 8 + wv;
        const short* g = Bt + (size_t)(scol0 + col) * KDIM + (size_t)(lane ^ (col & 7)) * 8;
        gload_lds16(g, &lds_b[col][0]);   // wave-uniform dest; HW adds lane*16
    }
    asm volatile("s_waitcnt vmcnt(0)" ::: "memory");
    __builtin_amdgcn_s_barrier();

    for (int c = (w >> 2); c < nch; c += bps) {
        const int r0 = c * CHUNK;
        const float* Arow = A + (size_t)(r0 + wv * 64) * KDIM;

        f32x4 acc[4][8];
#pragma unroll
        for (int i = 0; i < 4; ++i)
#pragma unroll
            for (int j = 0; j < 8; ++j)
                acc[i][j] = (f32x4){0.f, 0.f, 0.f, 0.f};

#pragma unroll
        for (int kt = 0; kt < 16; ++kt) {       // K = 16 x 32, no sync anywhere
            f32x4 raw[4][2];
#pragma unroll
            for (int fm = 0; fm < 4; ++fm) {
                const float* p = Arow + (size_t)(fm * 16 + lcol) * KDIM + kt * 32 + lhi * 8;
                raw[fm][0] = *(const f32x4*)p;
                raw[fm][1] = *(const f32x4*)(p + 4);
            }
            s16x8 bf[8];
#pragma unroll
            for (int fi = 0; fi < 8; ++fi) {
                int colb = fi * 16 + lcol;
                int ps = (kt * 4 + lhi) ^ (colb & 7);
                bf[fi] = *(const s16x8*)&lds_b[colb][ps * 8];
            }
            s16x8 af[4];
#pragma unroll
            for (int fm = 0; fm < 4; ++fm) {
                union { s16x8 s; uint32_t u[4]; } r;
                r.u[0] = pkbf(raw[fm][0][0], raw[fm][0][1]);
                r.u[1] = pkbf(raw[fm][0][2], raw[fm][0][3]);
                r.u[2] = pkbf(raw[fm][1][0], raw[fm][1][1]);
                r.u[3] = pkbf(raw[fm][1][2], raw[fm][1][3]);
                af[fm] = r.s;
            }
            __builtin_amdgcn_s_setprio(1);
#pragma unroll
            for (int fm = 0; fm < 4; ++fm)
#pragma unroll
                for (int fi = 0; fi < 8; ++fi)
                    acc[fm][fi] = __builtin_amdgcn_mfma_f32_16x16x32_bf16(af[fm], bf[fi], acc[fm][fi], 0, 0, 0);
            __builtin_amdgcn_s_setprio(0);
        }

        if constexpr (EPI == 0) {
#pragma unroll
            for (int fm = 0; fm < 4; ++fm)
#pragma unroll
                for (int fi = 0; fi < 8; ++fi) {
                    int col = scol0 + fi * 16 + lcol;
                    float bias = b1[col] + b2[col];
#pragma unroll
                    for (int reg = 0; reg < 4; ++reg) {
                        int row = r0 + wv * 64 + fm * 16 + lrg + reg;
                        outp[(size_t)row * KDIM + col] = acc[fm][fi][reg] + bias;
                    }
                }
        } else {
            // wave spans <=2 batch rows (64 < 196): preload both attdec rows
            const int rb0 = r0 + wv * 64;
            const int b0 = rb0 / NPIX;
            const int b1i = min(b0 + 1, BATCH - 1);
            float wfv[8], ad0[8], ad1[8];
#pragma unroll
            for (int fi = 0; fi < 8; ++fi) {
                int col = scol0 + fi * 16 + lcol;
                wfv[fi] = wfull[col];
                ad0[fi] = attdec[(size_t)b0 * KDIM + col];
                ad1[fi] = attdec[(size_t)b1i * KDIM + col];
            }
#pragma unroll
            for (int fm = 0; fm < 4; ++fm) {
#pragma unroll
                for (int reg = 0; reg < 4; ++reg) {
                    int row = rb0 + fm * 16 + lrg + reg;
                    bool hi = (row / NPIX) != b0;
                    float es = 0.f;
#pragma unroll
                    for (int fi = 0; fi < 8; ++fi) {
                        float ad = hi ? ad1[fi] : ad0[fi];
                        float v = acc[fm][fi][reg] + ad;
                        v = fmaxf(v, 0.f);
                        es = fmaf(v, wfv[fi], es);
                    }
#pragma unroll
                    for (int m = 1; m < 16; m <<= 1) es += __shfl_xor(es, m);
                    if (lcol == 0) outp[(size_t)slice * M + row] = es;
                }
            }
        }
    }
}

// One block per batch element: sum 4 slice partials, softmax over 196, write
// alpha, then context[b][e] = sum_p enc[b][p][e] * alpha[p].
__global__ void softmax_ctx(const float* __restrict__ enc, const float* __restrict__ energy4,
                            float* __restrict__ out) {
    const int b = blockIdx.x;
    const int t = threadIdx.x;  // 256
    __shared__ float sal[NPIX];
    __shared__ float wred[4];

    float e = -1e30f;
    if (t < NPIX) {
        float s = 0.f;
#pragma unroll
        for (int i = 0; i < 4; ++i) s += energy4[(size_t)i * M_MAIN + b * NPIX + t];
        e = s;
    }
    float m = e;
#pragma unroll
    for (int d = 1; d < 64; d <<= 1) m = fmaxf(m, __shfl_xor(m, d));
    if ((t & 63) == 0) wred[t >> 6] = m;
    __syncthreads();
    m = fmaxf(fmaxf(wred[0], wred[1]), fmaxf(wred[2], wred[3]));

    float ex = (t < NPIX) ? __expf(e - m) : 0.f;
    float sm = ex;
#pragma unroll
    for (int d = 1; d < 64; d <<= 1) sm += __shfl_xor(sm, d);
    __syncthreads();
    if ((t & 63) == 0) wred[t >> 6] = sm;
    __syncthreads();
    sm = wred[0] + wred[1] + wred[2] + wred[3];

    float al = ex / sm;
    if (t < NPIX) {
        sal[t] = al;
        out[BATCH * KDIM + b * NPIX + t] = al;
    }
    __syncthreads();

    float c0 = 0.f, c1 = 0.f;
    const float* eb = enc + (size_t)b * NPIX * KDIM;
    const int col = 2 * t;
#pragma unroll 4
    for (int p = 0; p < NPIX; ++p) {
        float a = sal[p];
        float2 v = *(const float2*)(eb + (size_t)p * KDIM + col);
        c0 = fmaf(v.x, a, c0);
        c1 = fmaf(v.y, a, c1);
    }
    out[b * KDIM + col] = c0;
    out[b * KDIM + col + 1] = c1;
}

extern "C" void kernel_launch(void* const* d_in, const int* in_sizes, int n_in,
                              void* d_out, int out_size, void* d_ws, size_t ws_size,
                              hipStream_t stream) {
    const float* encoder = (const float*)d_in[0];   // [512,196,512]
    const float* dec_h   = (const float*)d_in[1];   // [512,512]
    const float* W_enc   = (const float*)d_in[2];   // [512,512]
    const float* b_enc   = (const float*)d_in[3];   // [512]
    const float* W_dec   = (const float*)d_in[4];   // [512,512]
    const float* b_decv  = (const float*)d_in[5];   // [512]
    const float* w_full  = (const float*)d_in[6];   // [512]
    float* out = (float*)d_out;                     // context [512,512] ++ alpha [512,196]

    short* wt_enc = (short*)d_ws;                   // 512*512 bf16
    short* wt_dec = wt_enc + 512 * 512;             // 512*512 bf16
    float* attdec = (float*)(wt_dec + 512 * 512);   // [512][512] fp32 (incl. both biases)
    float* energy4 = attdec + 512 * 512;            // [4][100352] fp32 slice partials

    // 1) weight transpose + bf16 convert
    prep_w<<<dim3(512, 2), 512, 0, stream>>>(W_enc, W_dec, wt_enc, wt_dec);

    // 2) att_dec' = dec_h @ W_dec + b_dec + b_enc   (4 blocks: 1 chunk x 4 slices)
    gemm_fused<0><<<dim3(4), 512, 0, stream>>>(dec_h, 512, wt_dec,
                                               b_enc, b_decv, nullptr, nullptr, attdec);

    // 3) main fused GEMM -> energy slice partials (256 persistent blocks: 1/CU,
    //    B loaded once, 3-4 chunks of 512 rows each)
    gemm_fused<1><<<dim3(256), 512, 0, stream>>>(encoder, M_MAIN, wt_enc,
                                                 nullptr, nullptr, attdec, w_full, energy4);

    // 4) softmax + context
    softmax_ctx<<<dim3(BATCH), 256, 0, stream>>>(encoder, energy4, out);
}